// Round 1
// baseline (443.524 us; speedup 1.0000x reference)
//
#include <hip/hip_runtime.h>
#include <hip/hip_bf16.h>

namespace {

constexpr int kC    = 256;
constexpr int kH    = 192, kW = 192;
constexpr int kHW   = kH * kW;          // 36864
constexpr int kNBD  = 12;               // 16x16 blocks per spatial dim
constexpr int kNBLK = kNBD * kNBD;      // 144

typedef __attribute__((ext_vector_type(8))) short          bf16x8;
typedef __attribute__((ext_vector_type(8))) unsigned short u16x8;
typedef __attribute__((ext_vector_type(4))) unsigned short u16x4;
typedef __attribute__((ext_vector_type(4))) float          f32x4;

__device__ __forceinline__ unsigned short f2bf(float f) {
  union { float f; unsigned u; } x; x.f = f;
  unsigned r = x.u + 0x7fffu + ((x.u >> 16) & 1u);   // RNE
  return (unsigned short)(r >> 16);
}

__device__ __forceinline__ f32x4 mfma16(bf16x8 a, bf16x8 b, f32x4 c) {
  return __builtin_amdgcn_mfma_f32_16x16x32_bf16(a, b, c, 0, 0, 0);
}

// ---------------- K0: weights -> bf16 ----------------
__global__ void k_convw(const float* __restrict__ wq, const float* __restrict__ wk,
                        const float* __restrict__ wv, const float* __restrict__ wo,
                        unsigned short* __restrict__ dst) {
  int i = blockIdx.x * 256 + threadIdx.x;
  const float* s = (blockIdx.y == 0) ? wq : (blockIdx.y == 1) ? wk
                 : (blockIdx.y == 2) ? wv : wo;
  dst[(size_t)blockIdx.y * 65536 + i] = f2bf(s[i]);
}

// ---------------- K1: QKV projection ----------------
// grid 288 (256 px each), 512 thr. Stage x^T (px-major) bf16 in LDS, MFMA vs W[o][c].
__global__ __launch_bounds__(512, 2)
void k_qkv(const float* __restrict__ x, const unsigned short* __restrict__ wbf,
           unsigned short* __restrict__ qw, unsigned short* __restrict__ kw,
           unsigned short* __restrict__ vw) {
  __shared__ unsigned short xT[256][264];   // +8 pad: b128 reads 2-way conflict only
  const int tid = threadIdx.x;
  const int m0  = blockIdx.x * 256;
  const int b   = m0 / kHW;
  const int px0 = m0 % kHW;

  { // stage: lanes vary px consecutively (coalesced global, low-conflict LDS)
    const int cb0 = tid >> 4;   // 0..31
    const int pl  = tid & 15;
    for (int cb = 0; cb < 8; ++cb) {
      const int c = cb0 + cb * 32;
      const float* src = x + ((size_t)(b * kC + c)) * kHW + px0;
      #pragma unroll
      for (int kk = 0; kk < 16; ++kk) {
        const int p = pl + kk * 16;
        xT[p][c] = f2bf(src[p]);
      }
    }
  }
  __syncthreads();

  const int lane = tid & 63, wave = tid >> 6;
  const int l15 = lane & 15, l4 = lane >> 4;
  const int wm = wave >> 2, wn = wave & 3;   // wave tile: 128 px x 64 o

  unsigned short* outs[3] = {qw, kw, vw};
  for (int mat = 0; mat < 3; ++mat) {
    const unsigned short* wmat = wbf + (size_t)mat * 65536;
    f32x4 acc[8][4];
    #pragma unroll
    for (int pt = 0; pt < 8; ++pt)
      #pragma unroll
      for (int ot = 0; ot < 4; ++ot)
        acc[pt][ot] = (f32x4){0.f, 0.f, 0.f, 0.f};

    for (int kc = 0; kc < 8; ++kc) {
      bf16x8 bfr[4];
      #pragma unroll
      for (int ot = 0; ot < 4; ++ot)
        bfr[ot] = *(const bf16x8*)&wmat[(size_t)(wn * 64 + ot * 16 + l15) * 256 + kc * 32 + l4 * 8];
      #pragma unroll
      for (int pt = 0; pt < 8; ++pt) {
        bf16x8 af = *(const bf16x8*)&xT[wm * 128 + pt * 16 + l15][kc * 32 + l4 * 8];
        #pragma unroll
        for (int ot = 0; ot < 4; ++ot)
          acc[pt][ot] = mfma16(af, bfr[ot], acc[pt][ot]);
      }
    }
    unsigned short* dst = outs[mat] + ((size_t)b * kHW + px0) * 256;
    #pragma unroll
    for (int pt = 0; pt < 8; ++pt)
      #pragma unroll
      for (int ot = 0; ot < 4; ++ot)
        #pragma unroll
        for (int r = 0; r < 4; ++r) {
          const int pxl = wm * 128 + pt * 16 + l4 * 4 + r;  // C row
          const int oc  = wn * 64 + ot * 16 + l15;          // C col
          dst[(size_t)pxl * 256 + oc] = f2bf(acc[pt][ot][r]);
        }
  }
}

// ---------------- K2: block-local attention ----------------
// grid 2304 = (b,head,blk); 512 thr (8 waves x 32 queries).
// S^T = mfma(k, q) puts softmax axis in rows -> in-lane + shfl reduce.
__global__ __launch_bounds__(512, 2)
void k_attn(const unsigned short* __restrict__ qw, const unsigned short* __restrict__ kw,
            const unsigned short* __restrict__ vw, unsigned short* __restrict__ ow) {
  __shared__ unsigned short P[256][264];   // P[i][j] bf16 (stride 528B, 16B aligned)
  __shared__ unsigned short T[32][264];    // v^T, reused for O^T
  const int tid = threadIdx.x;
  int bx = blockIdx.x;
  const int blk = bx % kNBLK; bx /= kNBLK;
  const int head = bx & 7; const int b = bx >> 3;
  const int bh = blk / kNBD, bw = blk % kNBD;
  const int px00 = bh * 16 * kW + bw * 16;
  const size_t base = ((size_t)b * kHW) * 256 + head * 32;

  { // stage v^T[dd][j]; pair of lanes covers a full 64B head-slice per pixel
    const int j = tid >> 1, half = tid & 1;
    const int px = px00 + (j >> 4) * kW + (j & 15);
    const unsigned short* vp = vw + base + (size_t)px * 256 + half * 16;
    u16x8 a = *(const u16x8*)&vp[0];
    u16x8 c = *(const u16x8*)&vp[8];
    #pragma unroll
    for (int e = 0; e < 8; ++e) {
      T[half * 16 + e][j]     = a[e];
      T[half * 16 + 8 + e][j] = c[e];
    }
  }

  const int lane = tid & 63, wave = tid >> 6;
  const int l15 = lane & 15, l4 = lane >> 4;
  const f32x4 fz = {0.f, 0.f, 0.f, 0.f};

  // S^T = mfma(A=k, B=q): per wave 32 queries (cols), 256 keys (rows)
  bf16x8 qfr[2];
  #pragma unroll
  for (int it = 0; it < 2; ++it) {
    const int i  = wave * 32 + it * 16 + l15;
    const int px = px00 + (i >> 4) * kW + (i & 15);
    qfr[it] = *(const bf16x8*)&qw[base + (size_t)px * 256 + l4 * 8];
  }
  f32x4 s[16][2];
  #pragma unroll
  for (int jt = 0; jt < 16; ++jt) {
    const int px = px00 + jt * kW + l15;
    bf16x8 kf = *(const bf16x8*)&kw[base + (size_t)px * 256 + l4 * 8];
    s[jt][0] = mfma16(kf, qfr[0], fz);
    s[jt][1] = mfma16(kf, qfr[1], fz);
  }

  const float sc = 0.17677669529663687f;   // 1/sqrt(32)
  #pragma unroll
  for (int it = 0; it < 2; ++it) {
    float m = -3.0e38f;
    #pragma unroll
    for (int jt = 0; jt < 16; ++jt)
      #pragma unroll
      for (int r = 0; r < 4; ++r)
        m = fmaxf(m, s[jt][it][r]);
    m = fmaxf(m, __shfl_xor(m, 16));
    m = fmaxf(m, __shfl_xor(m, 32));
    float su = 0.f;
    #pragma unroll
    for (int jt = 0; jt < 16; ++jt)
      #pragma unroll
      for (int r = 0; r < 4; ++r) {
        float e = __expf((s[jt][it][r] - m) * sc);
        s[jt][it][r] = e;
        su += e;
      }
    su += __shfl_xor(su, 16);
    su += __shfl_xor(su, 32);
    const float inv = 1.f / su;
    const int i = wave * 32 + it * 16 + l15;
    #pragma unroll
    for (int jt = 0; jt < 16; ++jt) {   // 4 consecutive j per lane -> packed 8B store
      u16x4 pk;
      #pragma unroll
      for (int r = 0; r < 4; ++r) pk[r] = f2bf(s[jt][it][r] * inv);
      *(u16x4*)&P[i][jt * 16 + l4 * 4] = pk;
    }
  }
  __syncthreads();   // covers v^T staging + P writes

  // O^T = mfma(A=v^T, B=P)
  f32x4 oa[2][2];
  oa[0][0] = fz; oa[0][1] = fz; oa[1][0] = fz; oa[1][1] = fz;
  #pragma unroll
  for (int kt = 0; kt < 8; ++kt) {
    bf16x8 av0 = *(const bf16x8*)&T[l15][kt * 32 + l4 * 8];
    bf16x8 av1 = *(const bf16x8*)&T[16 + l15][kt * 32 + l4 * 8];
    bf16x8 bp0 = *(const bf16x8*)&P[wave * 32 + l15][kt * 32 + l4 * 8];
    bf16x8 bp1 = *(const bf16x8*)&P[wave * 32 + 16 + l15][kt * 32 + l4 * 8];
    oa[0][0] = mfma16(av0, bp0, oa[0][0]);
    oa[0][1] = mfma16(av0, bp1, oa[0][1]);
    oa[1][0] = mfma16(av1, bp0, oa[1][0]);
    oa[1][1] = mfma16(av1, bp1, oa[1][1]);
  }
  __syncthreads();   // all v^T reads done; safe to overwrite T with O^T
  #pragma unroll
  for (int ddt = 0; ddt < 2; ++ddt)
    #pragma unroll
    for (int it = 0; it < 2; ++it)
      #pragma unroll
      for (int r = 0; r < 4; ++r)
        T[ddt * 16 + l4 * 4 + r][wave * 32 + it * 16 + l15] = f2bf(oa[ddt][it][r]);
  __syncthreads();
  { // coalesced global write: lane pair = one pixel's 64B head slice
    const int i = tid >> 1, half = tid & 1;
    const int px = px00 + (i >> 4) * kW + (i & 15);
    u16x8 w0, w1;
    #pragma unroll
    for (int e = 0; e < 8; ++e) {
      w0[e] = T[half * 16 + e][i];
      w1[e] = T[half * 16 + 8 + e][i];
    }
    unsigned short* op = ow + base + (size_t)px * 256 + half * 16;
    *(u16x8*)&op[0] = w0;
    *(u16x8*)&op[8] = w1;
  }
}

// ---------------- K3: output projection + residual + LayerNorm ----------------
// out^T[o][px] = mfma(A=Wo, B=o_att) -> coalesced channel-planar fp32 stores.
__global__ __launch_bounds__(512, 2)
void k_proj_ln(const unsigned short* __restrict__ oatt, const unsigned short* __restrict__ wo,
               const float* __restrict__ x, const float* __restrict__ gamma,
               const float* __restrict__ beta, float* __restrict__ out) {
  __shared__ unsigned short WoL[256][264];
  __shared__ float gl[256], bl[256];
  const int tid = threadIdx.x;
  {
    const int o = tid >> 1, half = tid & 1;
    const unsigned short* src = wo + (size_t)o * 256 + half * 128;
    #pragma unroll
    for (int e = 0; e < 128; e += 8)
      *(bf16x8*)&WoL[o][half * 128 + e] = *(const bf16x8*)&src[e];
  }
  if (tid < 256) { gl[tid] = gamma[tid]; bl[tid] = beta[tid]; }
  __syncthreads();

  const int m0 = blockIdx.x * 256;
  const int b = m0 / kHW, px0 = m0 % kHW;
  const int lane = tid & 63, wave = tid >> 6;
  const int l15 = lane & 15, l4 = lane >> 4;
  const int pxw = px0 + wave * 32;   // wave tile: 256 o x 32 px

  f32x4 acc[16][2];
  #pragma unroll
  for (int ot = 0; ot < 16; ++ot) {
    acc[ot][0] = (f32x4){0.f, 0.f, 0.f, 0.f};
    acc[ot][1] = (f32x4){0.f, 0.f, 0.f, 0.f};
  }
  const unsigned short* ob = oatt + ((size_t)b * kHW) * 256;
  for (int kc = 0; kc < 8; ++kc) {
    bf16x8 b0 = *(const bf16x8*)&ob[(size_t)(pxw + l15) * 256 + kc * 32 + l4 * 8];
    bf16x8 b1 = *(const bf16x8*)&ob[(size_t)(pxw + 16 + l15) * 256 + kc * 32 + l4 * 8];
    #pragma unroll
    for (int ot = 0; ot < 16; ++ot) {
      bf16x8 af = *(const bf16x8*)&WoL[ot * 16 + l15][kc * 32 + l4 * 8];
      acc[ot][0] = mfma16(af, b0, acc[ot][0]);
      acc[ot][1] = mfma16(af, b1, acc[ot][1]);
    }
  }
  // residual + LN stats (per-px mean/var over all 256 channels)
  const float* xb = x + ((size_t)b * kC) * kHW;
  float s1[2] = {0.f, 0.f}, s2[2] = {0.f, 0.f};
  #pragma unroll
  for (int ot = 0; ot < 16; ++ot)
    #pragma unroll
    for (int pt = 0; pt < 2; ++pt)
      #pragma unroll
      for (int r = 0; r < 4; ++r) {
        const int oc = ot * 16 + l4 * 4 + r;
        const int px = pxw + pt * 16 + l15;
        float val = acc[ot][pt][r] + xb[(size_t)oc * kHW + px];
        acc[ot][pt][r] = val;
        s1[pt] += val;
        s2[pt] += val * val;
      }
  #pragma unroll
  for (int pt = 0; pt < 2; ++pt) {
    s1[pt] += __shfl_xor(s1[pt], 16);
    s1[pt] += __shfl_xor(s1[pt], 32);
    s2[pt] += __shfl_xor(s2[pt], 16);
    s2[pt] += __shfl_xor(s2[pt], 32);
  }
  float mean[2], rstd[2];
  #pragma unroll
  for (int pt = 0; pt < 2; ++pt) {
    mean[pt] = s1[pt] * (1.f / 256.f);
    float var = s2[pt] * (1.f / 256.f) - mean[pt] * mean[pt];
    rstd[pt] = rsqrtf(var + 1e-5f);
  }
  float* outb = out + ((size_t)b * kC) * kHW;
  #pragma unroll
  for (int ot = 0; ot < 16; ++ot)
    #pragma unroll
    for (int r = 0; r < 4; ++r) {
      const int oc = ot * 16 + l4 * 4 + r;
      const float g = gl[oc], be = bl[oc];
      #pragma unroll
      for (int pt = 0; pt < 2; ++pt) {
        const int px = pxw + pt * 16 + l15;
        outb[(size_t)oc * kHW + px] = (acc[ot][pt][r] - mean[pt]) * rstd[pt] * g + be;
      }
    }
}

} // namespace

extern "C" void kernel_launch(void* const* d_in, const int* in_sizes, int n_in,
                              void* d_out, int out_size, void* d_ws, size_t ws_size,
                              hipStream_t stream) {
  const float* x     = (const float*)d_in[0];
  const float* Wq    = (const float*)d_in[1];
  const float* Wk    = (const float*)d_in[2];
  const float* Wv    = (const float*)d_in[3];
  const float* Wo    = (const float*)d_in[4];
  const float* gamma = (const float*)d_in[5];
  const float* beta  = (const float*)d_in[6];
  float* out = (float*)d_out;

  const int nbatch = 2;
  const size_t per = (size_t)nbatch * kHW * 256;   // 18,874,368 elements

  unsigned short* wbf = (unsigned short*)d_ws;     // 4 x 65536 bf16 weights
  unsigned short* qws = wbf + 4 * 65536;
  unsigned short* kws = qws + per;
  unsigned short* vws = kws + per;
  unsigned short* ows = qws;   // alias q: each attn wg reads its q slice before
                               // (barrier-ordered) writing o to the same slice.

  k_convw<<<dim3(256, 4), 256, 0, stream>>>(Wq, Wk, Wv, Wo, wbf);
  k_qkv<<<(nbatch * kHW) / 256, 512, 0, stream>>>(x, wbf, qws, kws, vws);
  k_attn<<<nbatch * 8 * kNBLK, 512, 0, stream>>>(qws, kws, vws, ows);
  k_proj_ln<<<(nbatch * kHW) / 256, 512, 0, stream>>>(ows, wbf + 3 * 65536, x, gamma, beta, out);
}

// Round 2
// 241.589 us; speedup vs baseline: 1.8359x; 1.8359x over previous
//
#include <hip/hip_runtime.h>
#include <hip/hip_bf16.h>

namespace {

constexpr int kC    = 256;
constexpr int kH    = 192, kW = 192;
constexpr int kHW   = kH * kW;          // 36864
constexpr int kNBD  = 12;               // 16x16 blocks per spatial dim
constexpr int kNBLK = kNBD * kNBD;      // 144

typedef __attribute__((ext_vector_type(8))) short          bf16x8;
typedef __attribute__((ext_vector_type(8))) unsigned short u16x8;
typedef __attribute__((ext_vector_type(4))) unsigned short u16x4;
typedef __attribute__((ext_vector_type(4))) float          f32x4;

__device__ __forceinline__ unsigned short f2bf(float f) {
  union { float f; unsigned u; } x; x.f = f;
  unsigned r = x.u + 0x7fffu + ((x.u >> 16) & 1u);   // RNE
  return (unsigned short)(r >> 16);
}

__device__ __forceinline__ f32x4 mfma16(bf16x8 a, bf16x8 b, f32x4 c) {
  return __builtin_amdgcn_mfma_f32_16x16x32_bf16(a, b, c, 0, 0, 0);
}

// ---------------- K0: weights -> bf16 ----------------
__global__ void k_convw(const float* __restrict__ wq, const float* __restrict__ wk,
                        const float* __restrict__ wv, const float* __restrict__ wo,
                        unsigned short* __restrict__ dst) {
  int i = blockIdx.x * 256 + threadIdx.x;
  const float* s = (blockIdx.y == 0) ? wq : (blockIdx.y == 1) ? wk
                 : (blockIdx.y == 2) ? wv : wo;
  dst[(size_t)blockIdx.y * 65536 + i] = f2bf(s[i]);
}

// ---------------- K1: QKV projection (v2) ----------------
// 256 thr, tile 64 px x 256 oc, grid 1152. LDS 49KB -> 3 wg/CU.
// xT swizzled: 16B block cb stored at cb ^ (px&7)  (conflict-free b128 reads).
__global__ __launch_bounds__(256, 3)
void k_qkv(const float* __restrict__ x, const unsigned short* __restrict__ wbf,
           unsigned short* __restrict__ qw, unsigned short* __restrict__ kw,
           unsigned short* __restrict__ vw) {
  __shared__ unsigned short xTs[64 * 256];   // [px][256c], swizzled, 32KB
  __shared__ unsigned short oT[32 * 264];    // transpose staging, 16.5KB
  const int tid = threadIdx.x;
  const int w = tid >> 6, l = tid & 63;
  const int m0 = blockIdx.x * 64;
  const int b  = m0 / kHW;
  const int px0 = m0 % kHW;

  { // stage: lane l = px (64 contiguous floats/instr); wave w owns channels w*64..+63
    const float* xb = x + (size_t)b * kC * kHW + px0;
    #pragma unroll
    for (int i = 0; i < 64; i += 2) {
      const int c = w * 64 + i;
      float f0 = xb[(size_t)c * kHW + l];
      float f1 = xb[(size_t)(c + 1) * kHW + l];
      unsigned pk = (unsigned)f2bf(f0) | ((unsigned)f2bf(f1) << 16);
      const int cb = c >> 3;                              // c even -> pair in same block
      const int col = ((cb ^ (l & 7)) << 3) + (c & 7);
      *(unsigned*)&xTs[l * 256 + col] = pk;
    }
  }
  __syncthreads();

  const int lane = tid & 63;
  const int l15 = lane & 15, l4 = lane >> 4;

  unsigned short* outs[3] = {qw, kw, vw};
  for (int mat = 0; mat < 3; ++mat) {
    const unsigned short* wmat = wbf + (size_t)mat * 65536;
    f32x4 acc[4][4];   // [pt][ot]
    #pragma unroll
    for (int pt = 0; pt < 4; ++pt)
      #pragma unroll
      for (int ot = 0; ot < 4; ++ot)
        acc[pt][ot] = (f32x4){0.f, 0.f, 0.f, 0.f};

    for (int kc = 0; kc < 8; ++kc) {
      bf16x8 bfr[4];
      #pragma unroll
      for (int ot = 0; ot < 4; ++ot)
        bfr[ot] = *(const bf16x8*)&wmat[(size_t)(w * 64 + ot * 16 + l15) * 256 + kc * 32 + l4 * 8];
      #pragma unroll
      for (int pt = 0; pt < 4; ++pt) {
        const int cb = kc * 4 + l4;
        bf16x8 af = *(const bf16x8*)&xTs[(pt * 16 + l15) * 256 + ((cb ^ (l15 & 7)) << 3)];
        #pragma unroll
        for (int ot = 0; ot < 4; ++ot)
          acc[pt][ot] = mfma16(af, bfr[ot], acc[pt][ot]);
      }
    }
    // epilogue: LDS transpose in two 32-px halves, then coalesced u16x8 stores
    unsigned short* dst = outs[mat] + ((size_t)b * kHW + px0) * 256;
    for (int half = 0; half < 2; ++half) {
      __syncthreads();
      #pragma unroll
      for (int pt2 = 0; pt2 < 2; ++pt2) {
        const int pt = half * 2 + pt2;
        #pragma unroll
        for (int ot = 0; ot < 4; ++ot)
          #pragma unroll
          for (int r = 0; r < 4; ++r)
            oT[(pt2 * 16 + l4 * 4 + r) * 264 + w * 64 + ot * 16 + l15] = f2bf(acc[pt][ot][r]);
      }
      __syncthreads();
      const int row = tid >> 3, ocb = tid & 7;
      #pragma unroll
      for (int k2 = 0; k2 < 4; ++k2) {
        u16x8 vv = *(const u16x8*)&oT[row * 264 + ocb * 32 + k2 * 8];
        *(u16x8*)&dst[(size_t)(half * 32 + row) * 256 + ocb * 32 + k2 * 8] = vv;
      }
    }
  }
}

// ---------------- K2: block-local attention ----------------
// grid 2304 = (b,head,blk); 512 thr (8 waves x 32 queries).
// S^T = mfma(k, q) puts softmax axis in rows -> in-lane + shfl reduce.
__global__ __launch_bounds__(512, 2)
void k_attn(const unsigned short* __restrict__ qw, const unsigned short* __restrict__ kw,
            const unsigned short* __restrict__ vw, unsigned short* __restrict__ ow) {
  __shared__ unsigned short P[256][264];   // P[i][j] bf16 (stride 528B, 16B aligned)
  __shared__ unsigned short T[32][264];    // v^T, reused for O^T
  const int tid = threadIdx.x;
  int bx = blockIdx.x;
  const int blk = bx % kNBLK; bx /= kNBLK;
  const int head = bx & 7; const int b = bx >> 3;
  const int bh = blk / kNBD, bw = blk % kNBD;
  const int px00 = bh * 16 * kW + bw * 16;
  const size_t base = ((size_t)b * kHW) * 256 + head * 32;

  { // stage v^T[dd][j]; pair of lanes covers a full 64B head-slice per pixel
    const int j = tid >> 1, half = tid & 1;
    const int px = px00 + (j >> 4) * kW + (j & 15);
    const unsigned short* vp = vw + base + (size_t)px * 256 + half * 16;
    u16x8 a = *(const u16x8*)&vp[0];
    u16x8 c = *(const u16x8*)&vp[8];
    #pragma unroll
    for (int e = 0; e < 8; ++e) {
      T[half * 16 + e][j]     = a[e];
      T[half * 16 + 8 + e][j] = c[e];
    }
  }

  const int lane = tid & 63, wave = tid >> 6;
  const int l15 = lane & 15, l4 = lane >> 4;
  const f32x4 fz = {0.f, 0.f, 0.f, 0.f};

  // S^T = mfma(A=k, B=q): per wave 32 queries (cols), 256 keys (rows)
  bf16x8 qfr[2];
  #pragma unroll
  for (int it = 0; it < 2; ++it) {
    const int i  = wave * 32 + it * 16 + l15;
    const int px = px00 + (i >> 4) * kW + (i & 15);
    qfr[it] = *(const bf16x8*)&qw[base + (size_t)px * 256 + l4 * 8];
  }
  f32x4 s[16][2];
  #pragma unroll
  for (int jt = 0; jt < 16; ++jt) {
    const int px = px00 + jt * kW + l15;
    bf16x8 kf = *(const bf16x8*)&kw[base + (size_t)px * 256 + l4 * 8];
    s[jt][0] = mfma16(kf, qfr[0], fz);
    s[jt][1] = mfma16(kf, qfr[1], fz);
  }

  const float sc = 0.17677669529663687f;   // 1/sqrt(32)
  #pragma unroll
  for (int it = 0; it < 2; ++it) {
    float m = -3.0e38f;
    #pragma unroll
    for (int jt = 0; jt < 16; ++jt)
      #pragma unroll
      for (int r = 0; r < 4; ++r)
        m = fmaxf(m, s[jt][it][r]);
    m = fmaxf(m, __shfl_xor(m, 16));
    m = fmaxf(m, __shfl_xor(m, 32));
    float su = 0.f;
    #pragma unroll
    for (int jt = 0; jt < 16; ++jt)
      #pragma unroll
      for (int r = 0; r < 4; ++r) {
        float e = __expf((s[jt][it][r] - m) * sc);
        s[jt][it][r] = e;
        su += e;
      }
    su += __shfl_xor(su, 16);
    su += __shfl_xor(su, 32);
    const float inv = 1.f / su;
    const int i = wave * 32 + it * 16 + l15;
    #pragma unroll
    for (int jt = 0; jt < 16; ++jt) {   // 4 consecutive j per lane -> packed 8B store
      u16x4 pk;
      #pragma unroll
      for (int r = 0; r < 4; ++r) pk[r] = f2bf(s[jt][it][r] * inv);
      *(u16x4*)&P[i][jt * 16 + l4 * 4] = pk;
    }
  }
  __syncthreads();   // covers v^T staging + P writes

  // O^T = mfma(A=v^T, B=P)
  f32x4 oa[2][2];
  oa[0][0] = fz; oa[0][1] = fz; oa[1][0] = fz; oa[1][1] = fz;
  #pragma unroll
  for (int kt = 0; kt < 8; ++kt) {
    bf16x8 av0 = *(const bf16x8*)&T[l15][kt * 32 + l4 * 8];
    bf16x8 av1 = *(const bf16x8*)&T[16 + l15][kt * 32 + l4 * 8];
    bf16x8 bp0 = *(const bf16x8*)&P[wave * 32 + l15][kt * 32 + l4 * 8];
    bf16x8 bp1 = *(const bf16x8*)&P[wave * 32 + 16 + l15][kt * 32 + l4 * 8];
    oa[0][0] = mfma16(av0, bp0, oa[0][0]);
    oa[0][1] = mfma16(av0, bp1, oa[0][1]);
    oa[1][0] = mfma16(av1, bp0, oa[1][0]);
    oa[1][1] = mfma16(av1, bp1, oa[1][1]);
  }
  __syncthreads();   // all v^T reads done; safe to overwrite T with O^T
  #pragma unroll
  for (int ddt = 0; ddt < 2; ++ddt)
    #pragma unroll
    for (int it = 0; it < 2; ++it)
      #pragma unroll
      for (int r = 0; r < 4; ++r)
        T[ddt * 16 + l4 * 4 + r][wave * 32 + it * 16 + l15] = f2bf(oa[ddt][it][r]);
  __syncthreads();
  { // coalesced global write: lane pair = one pixel's 64B head slice
    const int i = tid >> 1, half = tid & 1;
    const int px = px00 + (i >> 4) * kW + (i & 15);
    u16x8 w0, w1;
    #pragma unroll
    for (int e = 0; e < 8; ++e) {
      w0[e] = T[half * 16 + e][i];
      w1[e] = T[half * 16 + 8 + e][i];
    }
    unsigned short* op = ow + base + (size_t)px * 256 + half * 16;
    *(u16x8*)&op[0] = w0;
    *(u16x8*)&op[8] = w1;
  }
}

// ---------------- K3: output projection + residual + LayerNorm (v2) ----------------
// 256 thr, tile 64 px x 256 oc, grid 1152. Wo read from L2 (no LDS staging).
// out^T[oc][px] = mfma(A=Wo rows, B=o_att rows) -> coalesced channel-planar stores.
__global__ __launch_bounds__(256, 3)
void k_proj_ln(const unsigned short* __restrict__ oatt, const unsigned short* __restrict__ wo,
               const float* __restrict__ x, const float* __restrict__ gamma,
               const float* __restrict__ beta, float* __restrict__ out) {
  __shared__ float pa[4][64], pb[4][64];   // per-wave partial s1/s2 per px
  const int tid = threadIdx.x, w = tid >> 6, lane = tid & 63;
  const int l15 = lane & 15, l4 = lane >> 4;
  const int m0 = blockIdx.x * 64;
  const int b = m0 / kHW, px0 = m0 % kHW;

  f32x4 acc[4][4];   // [ot][pt]: oc = w*64+ot*16+l4*4+r, px = pt*16+l15
  #pragma unroll
  for (int ot = 0; ot < 4; ++ot)
    #pragma unroll
    for (int pt = 0; pt < 4; ++pt)
      acc[ot][pt] = (f32x4){0.f, 0.f, 0.f, 0.f};

  const unsigned short* ob = oatt + ((size_t)b * kHW + px0) * 256;
  for (int kc = 0; kc < 8; ++kc) {
    bf16x8 bfr[4];
    #pragma unroll
    for (int pt = 0; pt < 4; ++pt)
      bfr[pt] = *(const bf16x8*)&ob[(size_t)(pt * 16 + l15) * 256 + kc * 32 + l4 * 8];
    #pragma unroll
    for (int ot = 0; ot < 4; ++ot) {
      bf16x8 af = *(const bf16x8*)&wo[(size_t)(w * 64 + ot * 16 + l15) * 256 + kc * 32 + l4 * 8];
      #pragma unroll
      for (int pt = 0; pt < 4; ++pt)
        acc[ot][pt] = mfma16(af, bfr[pt], acc[ot][pt]);
    }
  }

  // residual + per-px partial sums
  const float* xb = x + (size_t)b * kC * kHW + px0;
  float s1[4] = {0.f, 0.f, 0.f, 0.f}, s2[4] = {0.f, 0.f, 0.f, 0.f};
  #pragma unroll
  for (int ot = 0; ot < 4; ++ot)
    #pragma unroll
    for (int r = 0; r < 4; ++r) {
      const int oc = w * 64 + ot * 16 + l4 * 4 + r;
      #pragma unroll
      for (int pt = 0; pt < 4; ++pt) {
        float v = acc[ot][pt][r] + xb[(size_t)oc * kHW + pt * 16 + l15];
        acc[ot][pt][r] = v;
        s1[pt] += v;
        s2[pt] += v * v;
      }
    }
  #pragma unroll
  for (int pt = 0; pt < 4; ++pt) {
    s1[pt] += __shfl_xor(s1[pt], 16);
    s1[pt] += __shfl_xor(s1[pt], 32);
    s2[pt] += __shfl_xor(s2[pt], 16);
    s2[pt] += __shfl_xor(s2[pt], 32);
  }
  if (l4 == 0) {
    #pragma unroll
    for (int pt = 0; pt < 4; ++pt) {
      pa[w][pt * 16 + l15] = s1[pt];
      pb[w][pt * 16 + l15] = s2[pt];
    }
  }
  __syncthreads();
  float mean[4], rstd[4];
  #pragma unroll
  for (int pt = 0; pt < 4; ++pt) {
    const int px = pt * 16 + l15;
    float a = pa[0][px] + pa[1][px] + pa[2][px] + pa[3][px];
    float q = pb[0][px] + pb[1][px] + pb[2][px] + pb[3][px];
    mean[pt] = a * (1.f / 256.f);
    float var = q * (1.f / 256.f) - mean[pt] * mean[pt];
    rstd[pt] = rsqrtf(var + 1e-5f);
  }
  float* outb = out + (size_t)b * kC * kHW + px0;
  #pragma unroll
  for (int ot = 0; ot < 4; ++ot)
    #pragma unroll
    for (int r = 0; r < 4; ++r) {
      const int oc = w * 64 + ot * 16 + l4 * 4 + r;
      const float g = gamma[oc], be = beta[oc];
      #pragma unroll
      for (int pt = 0; pt < 4; ++pt)
        outb[(size_t)oc * kHW + pt * 16 + l15] = (acc[ot][pt][r] - mean[pt]) * rstd[pt] * g + be;
    }
}

} // namespace

extern "C" void kernel_launch(void* const* d_in, const int* in_sizes, int n_in,
                              void* d_out, int out_size, void* d_ws, size_t ws_size,
                              hipStream_t stream) {
  const float* x     = (const float*)d_in[0];
  const float* Wq    = (const float*)d_in[1];
  const float* Wk    = (const float*)d_in[2];
  const float* Wv    = (const float*)d_in[3];
  const float* Wo    = (const float*)d_in[4];
  const float* gamma = (const float*)d_in[5];
  const float* beta  = (const float*)d_in[6];
  float* out = (float*)d_out;

  const int nbatch = 2;
  const size_t per = (size_t)nbatch * kHW * 256;   // 18,874,368 elements

  unsigned short* wbf = (unsigned short*)d_ws;     // 4 x 65536 bf16 weights
  unsigned short* qws = wbf + 4 * 65536;
  unsigned short* kws = qws + per;
  unsigned short* vws = kws + per;
  unsigned short* ows = qws;   // alias q: each attn wg reads its q slice before
                               // (barrier-ordered) writing o to the same slice.

  k_convw<<<dim3(256, 4), 256, 0, stream>>>(Wq, Wk, Wv, Wo, wbf);
  k_qkv<<<(nbatch * kHW) / 64, 256, 0, stream>>>(x, wbf, qws, kws, vws);
  k_attn<<<nbatch * 8 * kNBLK, 512, 0, stream>>>(qws, kws, vws, ows);
  k_proj_ln<<<(nbatch * kHW) / 64, 256, 0, stream>>>(ows, wbf + 3 * 65536, x, gamma, beta, out);
}